// Round 1
// baseline (183.973 us; speedup 1.0000x reference)
//
#include <hip/hip_runtime.h>
#include <stdint.h>

#define NB 4
#define NN 8192
#define NE 2048
#define NC 64

typedef __bf16 bf16x8 __attribute__((ext_vector_type(8)));
typedef float f32x16 __attribute__((ext_vector_type(16)));

__device__ __forceinline__ unsigned short f2bf(float f) {
  union { float f; uint32_t u; } v; v.f = f;
  return (unsigned short)((v.u + 0x7FFFu + ((v.u >> 16) & 1u)) >> 16);
}

__device__ __forceinline__ bf16x8 ld_bf8(const void* p) {
  return *(const bf16x8*)p;
}

// ---------------------------------------------------------------------------
// K1: x' = x @ theta (fp32 compute), stored TRANSPOSED bf16: xt[b][o][n].
// n innermost = K-dim of pass-1 matmul -> contiguous A-fragment reads.
// ---------------------------------------------------------------------------
__global__ __launch_bounds__(256) void k_transform(
    const float* __restrict__ x, const float* __restrict__ theta,
    unsigned short* __restrict__ xt) {
  const int b = blockIdx.y, n0 = blockIdx.x * 64;
  __shared__ float xs[64][65];   // +1 pad: conflict-free row reads
  __shared__ float th[64][64];
  const int tid = threadIdx.x;
  for (int k = tid; k < 4096; k += 256) th[k >> 6][k & 63] = theta[k];
  const float* xrow = x + ((size_t)b * NN + n0) * NC;
  for (int k = tid; k < 4096; k += 256) xs[k >> 6][k & 63] = xrow[k];
  __syncthreads();
  const int w = tid >> 6, l = tid & 63;   // wave w: o-range [16w,16w+16); lane l: row n0+l
  float acc[16];
  #pragma unroll
  for (int j = 0; j < 16; ++j) acc[j] = 0.f;
  #pragma unroll 4
  for (int i = 0; i < 64; ++i) {
    const float xv = xs[l][i];
    const float4* t4 = (const float4*)(&th[i][w * 16]);
    const float4 a0 = t4[0], a1 = t4[1], a2 = t4[2], a3 = t4[3];
    acc[0]  += xv * a0.x; acc[1]  += xv * a0.y; acc[2]  += xv * a0.z; acc[3]  += xv * a0.w;
    acc[4]  += xv * a1.x; acc[5]  += xv * a1.y; acc[6]  += xv * a1.z; acc[7]  += xv * a1.w;
    acc[8]  += xv * a2.x; acc[9]  += xv * a2.y; acc[10] += xv * a2.z; acc[11] += xv * a2.w;
    acc[12] += xv * a3.x; acc[13] += xv * a3.y; acc[14] += xv * a3.z; acc[15] += xv * a3.w;
  }
  #pragma unroll
  for (int j = 0; j < 16; ++j)
    xt[((size_t)b * NC + (w * 16 + j)) * NN + n0 + l] = f2bf(acc[j]);
}

// ---------------------------------------------------------------------------
// K2: streams H once (256 MB, the HBM floor). Per block: batch b, e-strip of
// 64, n-range of 1024 (ksplit=8 -> 1024 blocks, 4/CU for BW latency hiding).
// Emits: xe_raw[b][o][e] partial sums (atomicAdd, fp32), deg_e column sums,
// and the packed bitmask bitsT[b][e/64][n] for pass 2.
// MFMA: C[o 64][e 64] += x'^T[o][n] * H[n][e], 32x32x16 bf16.
// ---------------------------------------------------------------------------
__global__ __launch_bounds__(256) void k_edge(
    const float* __restrict__ H, const unsigned short* __restrict__ xt,
    float* __restrict__ xe_raw, float* __restrict__ deg_e,
    unsigned long long* __restrict__ bitsT) {
  const int e0 = blockIdx.x * 64;
  const int b  = blockIdx.y;
  const int ks = blockIdx.z;
  const int tid = threadIdx.x, w = tid >> 6, l = tid & 63;
  const int q = l >> 5;

  __shared__ uint32_t ldsT[64][36];            // H^T tile: [e][n-pairs u32], stride 36 (16B-aligned rows)
  __shared__ unsigned long long mbuf[4][16];   // per-wave ballot staging
  __shared__ float dred[4][64];                // deg_e cross-wave reduce

  const int nbase = ks * (NN / 8);             // 1024 rows per block
  f32x16 acc;
  #pragma unroll
  for (int j = 0; j < 16; ++j) acc[j] = 0.f;
  float dacc = 0.f;                            // column sum for e = e0 + l

  const float* Hbase = H + (size_t)b * NN * NE + e0 + l;
  const unsigned short* Abase = xt + ((size_t)b * NC + ((w & 1) * 32 + (l & 31))) * NN;

  for (int t = 0; t < 16; ++t) {               // 16 tiles x 64 rows
    const int rowt = nbase + t * 64 + w * 16;  // wave w owns rows [rowt, rowt+16)
    #pragma unroll
    for (int j = 0; j < 8; ++j) {
      const int r0 = rowt + 2 * j;
      const float v0 = Hbase[(size_t)r0 * NE];
      const float v1 = Hbase[(size_t)(r0 + 1) * NE];
      dacc += v0 + v1;
      const unsigned long long m0 = __ballot(v0 != 0.f);
      const unsigned long long m1 = __ballot(v1 != 0.f);
      if (l == 0) { mbuf[w][2 * j] = m0; mbuf[w][2 * j + 1] = m1; }
      // bf16 pack: low = row r0, high = row r0+1 (n-pair) -> H^T tile
      const uint32_t p = (v0 != 0.f ? 0x3F80u : 0u) | (v1 != 0.f ? 0x3F800000u : 0u);
      ldsT[l][w * 8 + j] = p;
    }
    // bitmask out (within-wave LDS producer/consumer, no barrier needed)
    if (l < 16)
      bitsT[((size_t)b * 32 + blockIdx.x) * NN + rowt + l] = mbuf[w][l];
    __syncthreads();
    // wave w computes C[o 32][e 32]: o-half = w&1, e-half = w>>1
    const int ew = (w >> 1) * 32 + (l & 31);
    #pragma unroll
    for (int kk = 0; kk < 4; ++kk) {
      const bf16x8 av = ld_bf8(Abase + (nbase + t * 64 + kk * 16 + q * 8));
      const bf16x8 bv = ld_bf8(&ldsT[ew][kk * 8 + q * 4]);
      acc = __builtin_amdgcn_mfma_f32_32x32x16_bf16(av, bv, acc, 0, 0, 0);
    }
    __syncthreads();
  }
  // epilogue: atomic-accumulate partials (8 ksplit contenders per address)
  const int orow_base = (w & 1) * 32 + 4 * q;
  const int ecol = e0 + (w >> 1) * 32 + (l & 31);
  #pragma unroll
  for (int r = 0; r < 16; ++r) {
    const int orow = orow_base + (r & 3) + 8 * (r >> 2);
    atomicAdd(&xe_raw[((size_t)b * NC + orow) * NE + ecol], acc[r]);
  }
  dred[w][l] = dacc;
  __syncthreads();
  if (tid < 64) {
    const float s = dred[0][tid] + dred[1][tid] + dred[2][tid] + dred[3][tid];
    atomicAdd(&deg_e[(size_t)b * NE + e0 + tid], s);   // integer-valued: exact
  }
}

// ---------------------------------------------------------------------------
// K2b: xe_b[b][o][e] = bf16(xe_raw / deg_e). 512K elements.
// ---------------------------------------------------------------------------
__global__ __launch_bounds__(256) void k_edge_norm(
    const float* __restrict__ xe_raw, const float* __restrict__ deg_e,
    unsigned short* __restrict__ xe_b) {
  const int idx = blockIdx.x * 256 + threadIdx.x;   // < 4*64*2048
  const int e = idx & (NE - 1);
  const int b = idx >> 17;
  const float d = deg_e[b * NE + e];
  const float v = xe_raw[idx];
  xe_b[idx] = f2bf(d > 0.f ? v / d : 0.f);
}

// ---------------------------------------------------------------------------
// K3: xn = (H @ xe) / deg_n + bias. A = H from bits (expand->LDS bf16,
// XOR-swizzled 16B chunks), B = xe_b[b][o][e] read directly (L2-resident),
// deg_n = running popcount of the row bitmask. C[n 64][o 64] per block.
// ---------------------------------------------------------------------------
__global__ __launch_bounds__(256) void k_node(
    const unsigned long long* __restrict__ bitsT,
    const unsigned short* __restrict__ xe_b, const float* __restrict__ bias,
    float* __restrict__ out) {
  const int n0 = blockIdx.x * 64;
  const int b = blockIdx.y;
  const int tid = threadIdx.x, w = tid >> 6, l = tid & 63;
  const int q = l >> 5;

  __shared__ uint32_t ldsA[64][32];   // [n][e-pairs u32], chunk-XOR swizzled
  __shared__ float ldsDeg[64];

  const int erow = tid & 63, q4 = tid >> 6;   // expansion role: row, 16-e quarter
  unsigned long long pacc = 0;                // popcount (wave 0 threads only)

  f32x16 acc;
  #pragma unroll
  for (int j = 0; j < 16; ++j) acc[j] = 0.f;

  const unsigned short* Bbase = xe_b + ((size_t)b * NC + ((w & 1) * 32 + (l & 31))) * NE;
  const unsigned long long* bitrow = bitsT + (size_t)b * 32 * NN + n0;

  for (int et = 0; et < 32; ++et) {           // 32 e-tiles of 64
    const unsigned long long wbits = bitrow[(size_t)et * NN + erow];
    if (q4 == 0) pacc += (unsigned long long)__popcll(wbits);
    const uint32_t hb = (uint32_t)((wbits >> (16 * q4)) & 0xFFFFu);
    #pragma unroll
    for (int j2 = 0; j2 < 8; j2 += 2) {       // 4 x uint2 writes (8 u32 / thread)
      const uint32_t b0 = (hb >> (2 * j2)) & 3u;
      const uint32_t b1 = (hb >> (2 * j2 + 2)) & 3u;
      uint2 val;
      val.x = (b0 & 1u) * 0x3F80u + (b0 & 2u) * 0x1FC00000u;
      val.y = (b1 & 1u) * 0x3F80u + (b1 & 2u) * 0x1FC00000u;
      const int c = q4 * 8 + j2;
      const int cs = ((c >> 2) ^ (erow & 7)) * 4 + (c & 3);   // swizzled u32 col
      *(uint2*)&ldsA[erow][cs] = val;
    }
    __syncthreads();
    const int arow = (w >> 1) * 32 + (l & 31);  // wave: n-half = w>>1, o-half = w&1
    #pragma unroll
    for (int kk = 0; kk < 4; ++kk) {
      const int cs = ((kk * 2 + q) ^ (arow & 7)) * 4;
      const bf16x8 av = ld_bf8(&ldsA[arow][cs]);
      const bf16x8 bv = ld_bf8(Bbase + (et * 64 + kk * 16 + q * 8));
      acc = __builtin_amdgcn_mfma_f32_32x32x16_bf16(av, bv, acc, 0, 0, 0);
    }
    __syncthreads();
  }
  if (tid < 64) {
    const float dn = (float)pacc;
    ldsDeg[tid] = dn > 0.f ? 1.0f / dn : 0.f;
  }
  __syncthreads();
  const float bv0 = bias[(w & 1) * 32 + (l & 31)];
  const int rbase = (w >> 1) * 32 + 4 * q;
  const int ocol = (w & 1) * 32 + (l & 31);
  #pragma unroll
  for (int r = 0; r < 16; ++r) {
    const int row = rbase + (r & 3) + 8 * (r >> 2);
    out[((size_t)b * NN + n0 + row) * NC + ocol] = acc[r] * ldsDeg[row] + bv0;
  }
}

// ---------------------------------------------------------------------------
// ws layout: [0,4MB) xt bf16 | [4,12MB) bitsT | [12,14MB) xe_raw f32 |
// [14MB,+32KB) deg_e f32 | [15MB,+1MB) xe_b bf16.  Total 16 MB.
// ---------------------------------------------------------------------------
extern "C" void kernel_launch(void* const* d_in, const int* in_sizes, int n_in,
                              void* d_out, int out_size, void* d_ws, size_t ws_size,
                              hipStream_t stream) {
  const float* x     = (const float*)d_in[0];
  const float* H     = (const float*)d_in[1];
  const float* theta = (const float*)d_in[2];
  const float* bias  = (const float*)d_in[3];
  float* out = (float*)d_out;
  char* ws = (char*)d_ws;

  unsigned short* xt            = (unsigned short*)ws;
  unsigned long long* bitsT     = (unsigned long long*)(ws + (4 << 20));
  float* xe_raw                 = (float*)(ws + (12 << 20));
  float* deg_e                  = (float*)(ws + (14 << 20));
  unsigned short* xe_b          = (unsigned short*)(ws + (15 << 20));

  // zero the atomic accumulators every call (harness does not re-poison)
  hipMemsetAsync(ws + (12 << 20), 0, (2 << 20) + (64 << 10), stream);

  k_transform<<<dim3(NN / 64, NB), 256, 0, stream>>>(x, theta, xt);
  k_edge<<<dim3(NE / 64, NB, 8), 256, 0, stream>>>(H, xt, xe_raw, deg_e, bitsT);
  k_edge_norm<<<dim3((NB * NC * NE) / 256), 256, 0, stream>>>(xe_raw, deg_e, xe_b);
  k_node<<<dim3(NN / 64, NB), 256, 0, stream>>>(bitsT, xe_b, bias, out);
}

// Round 2
// 129.421 us; speedup vs baseline: 1.4215x; 1.4215x over previous
//
#include <hip/hip_runtime.h>
#include <stdint.h>

#define NB 4
#define NN 8192
#define NE 2048
#define NC 64

#define KSPLIT 16
#define NCHUNK (NN / KSPLIT)   // 512 rows per block
#define NTILES (NCHUNK / 64)   // 8 tiles of 64 rows

typedef __bf16 bf16x8 __attribute__((ext_vector_type(8)));
typedef float f32x16 __attribute__((ext_vector_type(16)));

__device__ __forceinline__ unsigned short f2bf(float f) {
  union { float f; uint32_t u; } v; v.f = f;
  return (unsigned short)((v.u + 0x7FFFu + ((v.u >> 16) & 1u)) >> 16);
}

__device__ __forceinline__ bf16x8 ld_bf8(const void* p) {
  return *(const bf16x8*)p;
}

// ---------------------------------------------------------------------------
// K1: x' = x @ theta (fp32 compute), stored TRANSPOSED bf16: xt[b][o][n].
// ---------------------------------------------------------------------------
__global__ __launch_bounds__(256) void k_transform(
    const float* __restrict__ x, const float* __restrict__ theta,
    unsigned short* __restrict__ xt) {
  const int b = blockIdx.y, n0 = blockIdx.x * 64;
  __shared__ float xs[64][65];
  __shared__ float th[64][64];
  const int tid = threadIdx.x;
  for (int k = tid; k < 4096; k += 256) th[k >> 6][k & 63] = theta[k];
  const float* xrow = x + ((size_t)b * NN + n0) * NC;
  for (int k = tid; k < 4096; k += 256) xs[k >> 6][k & 63] = xrow[k];
  __syncthreads();
  const int w = tid >> 6, l = tid & 63;
  float acc[16];
  #pragma unroll
  for (int j = 0; j < 16; ++j) acc[j] = 0.f;
  #pragma unroll 4
  for (int i = 0; i < 64; ++i) {
    const float xv = xs[l][i];
    const float4* t4 = (const float4*)(&th[i][w * 16]);
    const float4 a0 = t4[0], a1 = t4[1], a2 = t4[2], a3 = t4[3];
    acc[0]  += xv * a0.x; acc[1]  += xv * a0.y; acc[2]  += xv * a0.z; acc[3]  += xv * a0.w;
    acc[4]  += xv * a1.x; acc[5]  += xv * a1.y; acc[6]  += xv * a1.z; acc[7]  += xv * a1.w;
    acc[8]  += xv * a2.x; acc[9]  += xv * a2.y; acc[10] += xv * a2.z; acc[11] += xv * a2.w;
    acc[12] += xv * a3.x; acc[13] += xv * a3.y; acc[14] += xv * a3.z; acc[15] += xv * a3.w;
  }
  #pragma unroll
  for (int j = 0; j < 16; ++j)
    xt[((size_t)b * NC + (w * 16 + j)) * NN + n0 + l] = f2bf(acc[j]);
}

// ---------------------------------------------------------------------------
// K2: streams H once. ksplit=16 -> 2048 blocks = 8 blocks/CU = 32 waves/CU.
// Per tile: batched 16-load burst into regs -> ballot/pack -> double-buffered
// LDS; load(t+1) issued before MFMA(t); one barrier per tile.
// MFMA: C[o 64][e 64] += x'^T[o][n] * H[n][e], 32x32x16 bf16.
// ---------------------------------------------------------------------------
__global__ __launch_bounds__(256) void k_edge(
    const float* __restrict__ H, const unsigned short* __restrict__ xt,
    float* __restrict__ xe_raw, float* __restrict__ deg_e,
    unsigned long long* __restrict__ bitsT) {
  const int e0 = blockIdx.x * 64;
  const int b  = blockIdx.y;
  const int ks = blockIdx.z;
  const int tid = threadIdx.x, w = tid >> 6, l = tid & 63;
  const int q = l >> 5;

  __shared__ uint32_t ldsT[2][64][36];         // H^T tile (dbuf): [e][n-pair u32]
  __shared__ unsigned long long mbuf[4][16];   // per-wave ballot staging
  __shared__ float dred[4][64];                // deg_e cross-wave reduce

  const int nbase = ks * NCHUNK;
  f32x16 acc;
  #pragma unroll
  for (int j = 0; j < 16; ++j) acc[j] = 0.f;
  float dacc = 0.f;

  const float* Hbase = H + (size_t)b * NN * NE + (size_t)nbase * NE + e0 + l;
  const unsigned short* Abase =
      xt + ((size_t)b * NC + ((w & 1) * 32 + (l & 31))) * NN + nbase;
  const int ew = (w >> 1) * 32 + (l & 31);
  unsigned long long* bitsOut = bitsT + ((size_t)b * 32 + blockIdx.x) * NN + nbase;

  float v[16];

  #define LOAD_TILE(t)                                                   \
    {                                                                    \
      const int rowt = (t) * 64 + w * 16;                                \
      _Pragma("unroll")                                                  \
      for (int j = 0; j < 16; ++j) v[j] = Hbase[(size_t)(rowt + j) * NE];\
    }

  #define PROC_TILE(t, bufi)                                             \
    {                                                                    \
      const int rowt = (t) * 64 + w * 16;                                \
      _Pragma("unroll")                                                  \
      for (int i = 0; i < 8; ++i) {                                      \
        const float v0 = v[2 * i], v1 = v[2 * i + 1];                    \
        dacc += v0 + v1;                                                 \
        const unsigned long long m0 = __ballot(v0 != 0.f);               \
        const unsigned long long m1 = __ballot(v1 != 0.f);               \
        if (l == 0) { mbuf[w][2 * i] = m0; mbuf[w][2 * i + 1] = m1; }    \
        const uint32_t p = (v0 != 0.f ? 0x3F80u : 0u) |                  \
                           (v1 != 0.f ? 0x3F800000u : 0u);               \
        ldsT[bufi][l][w * 8 + i] = p;                                    \
      }                                                                  \
      if (l < 16) bitsOut[rowt + l] = mbuf[w][l];                        \
    }

  LOAD_TILE(0)
  PROC_TILE(0, 0)
  __syncthreads();

  for (int t = 0; t < NTILES; ++t) {
    const int cur = t & 1;
    if (t + 1 < NTILES) LOAD_TILE(t + 1)         // loads in flight over MFMA
    #pragma unroll
    for (int kk = 0; kk < 4; ++kk) {
      const bf16x8 av = ld_bf8(Abase + (t * 64 + kk * 16 + q * 8));
      const bf16x8 bv = ld_bf8(&ldsT[cur][ew][kk * 8 + q * 4]);
      acc = __builtin_amdgcn_mfma_f32_32x32x16_bf16(av, bv, acc, 0, 0, 0);
    }
    if (t + 1 < NTILES) PROC_TILE(t + 1, cur ^ 1)
    __syncthreads();
  }
  #undef LOAD_TILE
  #undef PROC_TILE

  // epilogue: atomic-accumulate partials (KSPLIT contenders per address)
  const int orow_base = (w & 1) * 32 + 4 * q;
  const int ecol = e0 + (w >> 1) * 32 + (l & 31);
  #pragma unroll
  for (int r = 0; r < 16; ++r) {
    const int orow = orow_base + (r & 3) + 8 * (r >> 2);
    atomicAdd(&xe_raw[((size_t)b * NC + orow) * NE + ecol], acc[r]);
  }
  dred[w][l] = dacc;
  __syncthreads();
  if (tid < 64) {
    const float s = dred[0][tid] + dred[1][tid] + dred[2][tid] + dred[3][tid];
    atomicAdd(&deg_e[(size_t)b * NE + e0 + tid], s);
  }
}

// ---------------------------------------------------------------------------
// K2b: xe_b[b][o][e] = bf16(xe_raw / deg_e).
// ---------------------------------------------------------------------------
__global__ __launch_bounds__(256) void k_edge_norm(
    const float* __restrict__ xe_raw, const float* __restrict__ deg_e,
    unsigned short* __restrict__ xe_b) {
  const int idx = blockIdx.x * 256 + threadIdx.x;
  const int e = idx & (NE - 1);
  const int b = idx >> 17;
  const float d = deg_e[b * NE + e];
  const float v = xe_raw[idx];
  xe_b[idx] = f2bf(d > 0.f ? v / d : 0.f);
}

// ---------------------------------------------------------------------------
// K3: xn = (H @ xe) / deg_n + bias. Bits -> LDS bf16 expand (XOR-swizzled),
// B-fragments hoisted + next-tile bitmask prefetched before the barrier.
// ---------------------------------------------------------------------------
__global__ __launch_bounds__(256) void k_node(
    const unsigned long long* __restrict__ bitsT,
    const unsigned short* __restrict__ xe_b, const float* __restrict__ bias,
    float* __restrict__ out) {
  const int n0 = blockIdx.x * 64;
  const int b = blockIdx.y;
  const int tid = threadIdx.x, w = tid >> 6, l = tid & 63;
  const int q = l >> 5;

  __shared__ uint32_t ldsA[64][32];
  __shared__ float ldsDeg[64];

  const int erow = tid & 63, q4 = tid >> 6;
  unsigned long long pacc = 0;

  f32x16 acc;
  #pragma unroll
  for (int j = 0; j < 16; ++j) acc[j] = 0.f;

  const unsigned short* Bbase = xe_b + ((size_t)b * NC + ((w & 1) * 32 + (l & 31))) * NE;
  const unsigned long long* bitrow = bitsT + (size_t)b * 32 * NN + n0;

  unsigned long long wb = bitrow[erow];          // prefetch et=0
  for (int et = 0; et < 32; ++et) {
    const unsigned long long wbits = wb;
    if (et + 1 < 32) wb = bitrow[(size_t)(et + 1) * NN + erow];
    bf16x8 bvv[4];
    #pragma unroll
    for (int kk = 0; kk < 4; ++kk)
      bvv[kk] = ld_bf8(Bbase + (et * 64 + kk * 16 + q * 8));

    if (q4 == 0) pacc += (unsigned long long)__popcll(wbits);
    const uint32_t hb = (uint32_t)((wbits >> (16 * q4)) & 0xFFFFu);
    #pragma unroll
    for (int j2 = 0; j2 < 8; j2 += 2) {
      const uint32_t b0 = (hb >> (2 * j2)) & 3u;
      const uint32_t b1 = (hb >> (2 * j2 + 2)) & 3u;
      uint2 val;
      val.x = (b0 & 1u) * 0x3F80u + (b0 & 2u) * 0x1FC00000u;
      val.y = (b1 & 1u) * 0x3F80u + (b1 & 2u) * 0x1FC00000u;
      const int c = q4 * 8 + j2;
      const int cs = ((c >> 2) ^ (erow & 7)) * 4 + (c & 3);
      *(uint2*)&ldsA[erow][cs] = val;
    }
    __syncthreads();
    const int arow = (w >> 1) * 32 + (l & 31);
    #pragma unroll
    for (int kk = 0; kk < 4; ++kk) {
      const int cs = ((kk * 2 + q) ^ (arow & 7)) * 4;
      const bf16x8 av = ld_bf8(&ldsA[arow][cs]);
      acc = __builtin_amdgcn_mfma_f32_32x32x16_bf16(av, bvv[kk], acc, 0, 0, 0);
    }
    __syncthreads();
  }
  if (tid < 64) {
    const float dn = (float)pacc;
    ldsDeg[tid] = dn > 0.f ? 1.0f / dn : 0.f;
  }
  __syncthreads();
  const float bv0 = bias[(w & 1) * 32 + (l & 31)];
  const int rbase = (w >> 1) * 32 + 4 * q;
  const int ocol = (w & 1) * 32 + (l & 31);
  #pragma unroll
  for (int r = 0; r < 16; ++r) {
    const int row = rbase + (r & 3) + 8 * (r >> 2);
    out[((size_t)b * NN + n0 + row) * NC + ocol] = acc[r] * ldsDeg[row] + bv0;
  }
}

// ---------------------------------------------------------------------------
// ws layout: [0,4MB) xt bf16 | [4,12MB) bitsT | [12,14MB) xe_raw f32 |
// [14,+64KB) deg_e f32 | [15MB,+1MB) xe_b bf16.
// ---------------------------------------------------------------------------
extern "C" void kernel_launch(void* const* d_in, const int* in_sizes, int n_in,
                              void* d_out, int out_size, void* d_ws, size_t ws_size,
                              hipStream_t stream) {
  const float* x     = (const float*)d_in[0];
  const float* H     = (const float*)d_in[1];
  const float* theta = (const float*)d_in[2];
  const float* bias  = (const float*)d_in[3];
  float* out = (float*)d_out;
  char* ws = (char*)d_ws;

  unsigned short* xt        = (unsigned short*)ws;
  unsigned long long* bitsT = (unsigned long long*)(ws + (4 << 20));
  float* xe_raw             = (float*)(ws + (12 << 20));
  float* deg_e              = (float*)(ws + (14 << 20));
  unsigned short* xe_b      = (unsigned short*)(ws + (15 << 20));

  hipMemsetAsync(ws + (12 << 20), 0, (2 << 20) + (64 << 10), stream);

  k_transform<<<dim3(NN / 64, NB), 256, 0, stream>>>(x, theta, xt);
  k_edge<<<dim3(NE / 64, NB, KSPLIT), 256, 0, stream>>>(H, xt, xe_raw, deg_e, bitsT);
  k_edge_norm<<<dim3((NB * NC * NE) / 256), 256, 0, stream>>>(xe_raw, deg_e, xe_b);
  k_node<<<dim3(NN / 64, NB), 256, 0, stream>>>(bitsT, xe_b, bias, out);
}